// Round 1
// baseline (593.954 us; speedup 1.0000x reference)
//
#include <hip/hip_runtime.h>

// CrossAttention: out = softmax((S2 Wq)(S1 Wk)^T) (S1 Wv) Wo + bo
// Refactored: Wvo = Wv@Wo (512x512);  V'' = S1@Wvo + bo;  out = softmax(QK^T) @ V''
// All GEMMs in fp16 MFMA (16x16x32), fp32 accumulate. Logit sigma ~10.7 -> fp16
// keeps absolute logit error ~0.011, well under the 3.25e-2 absmax budget.

typedef _Float16 h_t;
typedef _Float16 h8 __attribute__((ext_vector_type(8)));
typedef _Float16 h4 __attribute__((ext_vector_type(4)));
typedef float f4 __attribute__((ext_vector_type(4)));

#define MFMA16(a, b, c) __builtin_amdgcn_mfma_f32_16x16x32_f16(a, b, c, 0, 0, 0)

typedef const __attribute__((address_space(1))) void* gas_t;
typedef __attribute__((address_space(3))) void* las_t;

__device__ __forceinline__ void gl2lds16(const void* g, void* l) {
    // async global->LDS, 16B per lane; LDS dest = wave-uniform base + lane*16
    __builtin_amdgcn_global_load_lds((gas_t)g, (las_t)l, 16, 0, 0);
}

// ---------------- cast fp32 -> fp16 (4 elems / thread) ----------------
__global__ __launch_bounds__(256) void k_cast(const float* __restrict__ in,
                                              h_t* __restrict__ out, int n4) {
    int i = blockIdx.x * 256 + threadIdx.x;
    if (i >= n4) return;
    float4 v = *((const float4*)in + i);
    h4 h = {(h_t)v.x, (h_t)v.y, (h_t)v.z, (h_t)v.w};
    *((h4*)out + i) = h;
}

// ---------------- transpose+cast: in [K][N] f32 -> out [N][K] f16 ----------------
__global__ __launch_bounds__(256) void k_transpose_cast(const float* __restrict__ in,
                                                        h_t* __restrict__ out,
                                                        int K, int N) {
    __shared__ float tile[32][33];
    int x = threadIdx.x & 31, y = threadIdx.x >> 5;
    int kb = blockIdx.y * 32, nb = blockIdx.x * 32;
#pragma unroll
    for (int j = 0; j < 4; j++)
        tile[y + j * 8][x] = in[(size_t)(kb + y + j * 8) * N + nb + x];
    __syncthreads();
#pragma unroll
    for (int j = 0; j < 4; j++)
        out[(size_t)(nb + y + j * 8) * K + kb + x] = (h_t)tile[x][y + j * 8];
}

// ---------------- Wvot[d][c] = sum_e Wv[c][e] * Wo[e][d]  (f32 acc -> f16) ---------
// Wv [512][1024], Wo [1024][512]. 128 blocks x 4 c-rows each; d split across threads.
__global__ __launch_bounds__(256) void k_wvo(const float* __restrict__ Wv,
                                             const float* __restrict__ Wo,
                                             h_t* __restrict__ Wvot) {
    __shared__ float wv[4][1024];
    int t = threadIdx.x;
    int c0 = blockIdx.x * 4;
#pragma unroll
    for (int i = 0; i < 4; i++)
        *(float4*)&wv[i][t * 4] = *(const float4*)&Wv[(size_t)(c0 + i) * 1024 + t * 4];
    __syncthreads();
    float a0[4] = {0.f, 0.f, 0.f, 0.f}, a1[4] = {0.f, 0.f, 0.f, 0.f};
#pragma unroll 4
    for (int e = 0; e < 1024; e++) {
        float w0 = Wo[(size_t)e * 512 + t];
        float w1 = Wo[(size_t)e * 512 + t + 256];
#pragma unroll
        for (int i = 0; i < 4; i++) {
            a0[i] += wv[i][e] * w0;
            a1[i] += wv[i][e] * w1;
        }
    }
    h4 h0 = {(h_t)a0[0], (h_t)a0[1], (h_t)a0[2], (h_t)a0[3]};
    h4 h1 = {(h_t)a1[0], (h_t)a1[1], (h_t)a1[2], (h_t)a1[3]};
    *(h4*)&Wvot[(size_t)t * 512 + c0] = h0;
    *(h4*)&Wvot[(size_t)(t + 256) * 512 + c0] = h1;
}

// ---------------- m97-style NT GEMM: C[M][N] f16 = A[M][K] x Bt[N][K]^T ------------
// 128x128 tile, BK=64, 256 threads (4 waves, 64x64 each), global_load_lds staging,
// XOR-swizzled LDS chunks (2-way bank aliasing only, which is free).
__global__ __launch_bounds__(256) void k_gemm(const h_t* __restrict__ A,
                                              const h_t* __restrict__ Bt,
                                              h_t* __restrict__ C,
                                              int M, int N, int K) {
    __shared__ h_t As[128 * 64];
    __shared__ h_t Bs[128 * 64];
    int t = threadIdx.x, w = t >> 6, lane = t & 63;
    int q16 = lane >> 4, l16 = lane & 15;
    size_t m0 = (size_t)blockIdx.x * 128, n0 = (size_t)blockIdx.y * 128;
    int wr = (w >> 1) * 64, wc = (w & 1) * 64;
    f4 acc[4][4] = {};

    for (int k0 = 0; k0 < K; k0 += 64) {
#pragma unroll
        for (int j = 0; j < 4; j++) {
            int q = w * 4 + j;
            int row = q * 8 + (lane >> 3);
            int ks = (((lane & 7) ^ (row & 7)) << 3);  // swizzled source chunk
            gl2lds16(A + (m0 + row) * K + k0 + ks, &As[q * 512]);
            gl2lds16(Bt + (n0 + row) * K + k0 + ks, &Bs[q * 512]);
        }
        __syncthreads();
#pragma unroll
        for (int ks = 0; ks < 2; ks++) {
            h8 av[4], bv[4];
#pragma unroll
            for (int i = 0; i < 4; i++) {
                int row = wr + i * 16 + l16;
                int ch = ks * 4 + q16;
                av[i] = *(const h8*)&As[row * 64 + ((ch ^ (row & 7)) << 3)];
            }
#pragma unroll
            for (int j = 0; j < 4; j++) {
                int row = wc + j * 16 + l16;
                int ch = ks * 4 + q16;
                bv[j] = *(const h8*)&Bs[row * 64 + ((ch ^ (row & 7)) << 3)];
            }
#pragma unroll
            for (int i = 0; i < 4; i++)
#pragma unroll
                for (int j = 0; j < 4; j++)
                    acc[i][j] = MFMA16(av[i], bv[j], acc[i][j]);
        }
        __syncthreads();
    }
    // epilogue: C/D layout col=lane&15, row=(lane>>4)*4+reg
#pragma unroll
    for (int i = 0; i < 4; i++) {
        size_t r0 = m0 + wr + i * 16 + q16 * 4;
#pragma unroll
        for (int j = 0; j < 4; j++) {
            size_t c = n0 + wc + j * 16 + l16;
#pragma unroll
            for (int r = 0; r < 4; r++)
                C[(r0 + r) * N + c] = (h_t)acc[i][j][r];
        }
    }
}

// ---------------- V'' GEMM: same, but +bias and transposed store ------------------
// Vt[b][d][n] = S1[b][n][:] @ Wvot[d][:] + bo[d]   (n fastest -> contiguous h4 store)
__global__ __launch_bounds__(256) void k_gemm_vt(const h_t* __restrict__ A,
                                                 const h_t* __restrict__ Bt,
                                                 const float* __restrict__ bo,
                                                 h_t* __restrict__ Vt,
                                                 int M, int N, int K) {
    __shared__ h_t As[128 * 64];
    __shared__ h_t Bs[128 * 64];
    int t = threadIdx.x, w = t >> 6, lane = t & 63;
    int q16 = lane >> 4, l16 = lane & 15;
    size_t m0 = (size_t)blockIdx.x * 128, n0 = (size_t)blockIdx.y * 128;
    int wr = (w >> 1) * 64, wc = (w & 1) * 64;
    f4 acc[4][4] = {};

    for (int k0 = 0; k0 < K; k0 += 64) {
#pragma unroll
        for (int j = 0; j < 4; j++) {
            int q = w * 4 + j;
            int row = q * 8 + (lane >> 3);
            int ks = (((lane & 7) ^ (row & 7)) << 3);
            gl2lds16(A + (m0 + row) * K + k0 + ks, &As[q * 512]);
            gl2lds16(Bt + (n0 + row) * K + k0 + ks, &Bs[q * 512]);
        }
        __syncthreads();
#pragma unroll
        for (int ks = 0; ks < 2; ks++) {
            h8 av[4], bv[4];
#pragma unroll
            for (int i = 0; i < 4; i++) {
                int row = wr + i * 16 + l16;
                int ch = ks * 4 + q16;
                av[i] = *(const h8*)&As[row * 64 + ((ch ^ (row & 7)) << 3)];
            }
#pragma unroll
            for (int j = 0; j < 4; j++) {
                int row = wc + j * 16 + l16;
                int ch = ks * 4 + q16;
                bv[j] = *(const h8*)&Bs[row * 64 + ((ch ^ (row & 7)) << 3)];
            }
#pragma unroll
            for (int i = 0; i < 4; i++)
#pragma unroll
                for (int j = 0; j < 4; j++)
                    acc[i][j] = MFMA16(av[i], bv[j], acc[i][j]);
        }
        __syncthreads();
    }
#pragma unroll
    for (int i = 0; i < 4; i++) {
        size_t gm = m0 + wr + i * 16 + q16 * 4;  // 4 consecutive rows, same batch
        size_t b = gm >> 11;
        size_t n = gm & 2047;
#pragma unroll
        for (int j = 0; j < 4; j++) {
            size_t d = n0 + wc + j * 16 + l16;
            float bias = bo[d];
            h4 hv = {(h_t)(acc[i][j][0] + bias), (h_t)(acc[i][j][1] + bias),
                     (h_t)(acc[i][j][2] + bias), (h_t)(acc[i][j][3] + bias)};
            *(h4*)&Vt[(b * 512 + d) * 2048 + n] = hv;
        }
    }
}

// ---------------- fused flash attention ----------------
// Grid 256 blocks (1/CU), 512 threads (8 waves). Q-tile 64 rows in registers
// (128 VGPR/lane), K-tile 64 keys staged in LDS (1024-deep inner, 256-chunks),
// online softmax in LDS, PV with d_v=512 split 64 cols/wave, V read from L2.
// b = blockIdx&7 -> same-batch wgs land on one XCD (round-robin dispatch heuristic).
__global__ __launch_bounds__(512) void k_attn(const h_t* __restrict__ Qh,
                                              const h_t* __restrict__ Kh,
                                              const h_t* __restrict__ Vt,
                                              float* __restrict__ Out) {
    __shared__ h_t Ks[64 * 256];     // 32 KB, XOR-swizzled 16B chunks
    __shared__ float Ss[64 * 65];    // 16.6 KB scores, stride 65 (conflict-free cols)
    __shared__ h_t Ps[64 * 64];      // 8 KB probs, XOR-swizzled
    __shared__ float red[8 * 64];
    __shared__ float mrow[64], lrow[64], arow[64];

    int t = threadIdx.x, w = t >> 6, lane = t & 63;
    int q16 = lane >> 4, l16 = lane & 15;
    int b = blockIdx.x & 7;
    int qt = blockIdx.x >> 3;
    int q0 = qt * 64;
    int rb = w >> 1;        // S row band (0..3)
    int cp = (w & 1) * 2;   // S col tiles cp, cp+1

    if (t < 64) { mrow[t] = -1e30f; lrow[t] = 0.f; }

    // Q fragments: rows rb*16+l16, k = f*32 + q16*8 .. +8
    h8 qf[32];
    {
        size_t qrow = (size_t)b * 2048 + q0 + rb * 16 + l16;
        const h_t* qp = Qh + qrow * 1024 + q16 * 8;
#pragma unroll
        for (int f = 0; f < 32; f++) qf[f] = *(const h8*)(qp + f * 32);
    }
    f4 oacc[4][4] = {};
    const h_t* Kbase = Kh + (size_t)b * 2048 * 1024;
    const h_t* Vbase = Vt + (size_t)b * 512 * 2048;

    for (int kt = 0; kt < 32; kt++) {
        int kb = kt * 64;
        f4 sacc[2] = {};
        // ---- S = Q K^T over inner 1024, staged in 4 chunks of 256 ----
#pragma unroll
        for (int c4 = 0; c4 < 4; c4++) {
#pragma unroll
            for (int j = 0; j < 4; j++) {
                int qch = w * 4 + j;
                int row = qch * 2 + (lane >> 5);
                int kg = lane & 31;
                int kgsrc = kg ^ (row & 7);
                gl2lds16(Kbase + (size_t)(kb + row) * 1024 + c4 * 256 + kgsrc * 8,
                         &Ks[qch * 512]);
            }
            __syncthreads();
#pragma unroll
            for (int ks = 0; ks < 8; ks++) {
                h8 bv0, bv1;
                {
                    int row = (cp + 0) * 16 + l16;
                    int ch = ks * 4 + q16;
                    bv0 = *(const h8*)&Ks[row * 256 + ((ch ^ (row & 7)) << 3)];
                }
                {
                    int row = (cp + 1) * 16 + l16;
                    int ch = ks * 4 + q16;
                    bv1 = *(const h8*)&Ks[row * 256 + ((ch ^ (row & 7)) << 3)];
                }
                sacc[0] = MFMA16(qf[c4 * 8 + ks], bv0, sacc[0]);
                sacc[1] = MFMA16(qf[c4 * 8 + ks], bv1, sacc[1]);
            }
            __syncthreads();
        }
        // ---- scores -> LDS ----
#pragma unroll
        for (int tt = 0; tt < 2; tt++) {
            int col = (cp + tt) * 16 + l16;
#pragma unroll
            for (int r = 0; r < 4; r++) {
                int row = rb * 16 + q16 * 4 + r;
                Ss[row * 65 + col] = sacc[tt][r];
            }
        }
        __syncthreads();
        // ---- online softmax (rows x 8 col-groups of 8) ----
        int srow = t & 63, g = t >> 6;
        const float* ssp = &Ss[srow * 65 + g * 8];
        float pm = -1e30f;
#pragma unroll
        for (int c = 0; c < 8; c++) pm = fmaxf(pm, ssp[c]);
        red[g * 64 + srow] = pm;
        __syncthreads();
        if (t < 64) {
            float m2 = red[t];
#pragma unroll
            for (int g2 = 1; g2 < 8; g2++) m2 = fmaxf(m2, red[g2 * 64 + t]);
            float mo = mrow[t];
            float mn = fmaxf(mo, m2);
            mrow[t] = mn;
            arow[t] = __expf(mo - mn);
        }
        __syncthreads();
        {
            float mn = mrow[srow];
            float ps = 0.f;
            h8 pv;
#pragma unroll
            for (int c = 0; c < 8; c++) {
                float e = __expf(ssp[c] - mn);
                ps += e;
                pv[c] = (h_t)e;
            }
            int slot = g ^ (srow & 7);
            *(h8*)&Ps[srow * 64 + slot * 8] = pv;
            red[g * 64 + srow] = ps;
        }
        __syncthreads();
        if (t < 64) {
            float s = 0.f;
#pragma unroll
            for (int g2 = 0; g2 < 8; g2++) s += red[g2 * 64 + t];
            lrow[t] = lrow[t] * arow[t] + s;
        }
        __syncthreads();
        // ---- rescale O, then O += P @ V'' (wave owns 64 of 512 d-cols) ----
#pragma unroll
        for (int i = 0; i < 4; i++) {
#pragma unroll
            for (int r = 0; r < 4; r++) {
                float al = arow[i * 16 + q16 * 4 + r];
#pragma unroll
                for (int j = 0; j < 4; j++) oacc[i][j][r] *= al;
            }
        }
#pragma unroll
        for (int ks = 0; ks < 2; ks++) {
            h8 pf[4], vf[4];
#pragma unroll
            for (int j = 0; j < 4; j++) {
                int d = w * 64 + j * 16 + l16;
                vf[j] = *(const h8*)(Vbase + (size_t)d * 2048 + kb + ks * 32 + q16 * 8);
            }
#pragma unroll
            for (int i = 0; i < 4; i++) {
                int row = i * 16 + l16;
                int ch = ks * 4 + q16;
                pf[i] = *(const h8*)&Ps[row * 64 + ((ch ^ (row & 7)) << 3)];
            }
#pragma unroll
            for (int i = 0; i < 4; i++)
#pragma unroll
                for (int j = 0; j < 4; j++)
                    oacc[i][j] = MFMA16(pf[i], vf[j], oacc[i][j]);
        }
        __syncthreads();
    }
    // ---- epilogue: normalize by l, store fp32 ----
#pragma unroll
    for (int i = 0; i < 4; i++) {
#pragma unroll
        for (int r = 0; r < 4; r++) {
            int row = i * 16 + q16 * 4 + r;
            float inv = 1.f / lrow[row];
            size_t orow = ((size_t)b * 2048 + q0 + row) * 512;
#pragma unroll
            for (int j = 0; j < 4; j++) {
                int d = w * 64 + j * 16 + l16;
                Out[orow + d] = oacc[i][j][r] * inv;
            }
        }
    }
}

// ---------------- host ----------------
extern "C" void kernel_launch(void* const* d_in, const int* in_sizes, int n_in,
                              void* d_out, int out_size, void* d_ws, size_t ws_size,
                              hipStream_t stream) {
    const float* S1 = (const float*)d_in[0];
    const float* S2 = (const float*)d_in[1];
    const float* Wq = (const float*)d_in[2];
    const float* Wk = (const float*)d_in[3];
    const float* Wv = (const float*)d_in[4];
    const float* Wo = (const float*)d_in[5];
    const float* bo = (const float*)d_in[6];
    float* Out = (float*)d_out;

    char* ws = (char*)d_ws;
    h_t* S2h  = (h_t*)(ws);                 // 16 MB   [16384][512]
    h_t* S1h  = (h_t*)(ws + 16777216);      // 16 MB   [16384][512]
    h_t* Wqt  = (h_t*)(ws + 33554432);      // 1 MB    [1024][512]
    h_t* Wkt  = (h_t*)(ws + 34603008);      // 1 MB    [1024][512]
    h_t* Wvot = (h_t*)(ws + 35651584);      // 0.5 MB  [512][512]
    h_t* Qh   = (h_t*)(ws + 36175872);      // 32 MB   [16384][1024]
    h_t* Kh   = (h_t*)(ws + 69730304);      // 32 MB   [16384][1024]
    h_t* Vt   = (h_t*)(ws + 103284736);     // 16 MB   [8][512][2048]
    // total 120,061,952 bytes

    int nS = 8 * 2048 * 512;
    k_cast<<<nS / 4 / 256, 256, 0, stream>>>(S2, S2h, nS / 4);
    k_cast<<<nS / 4 / 256, 256, 0, stream>>>(S1, S1h, nS / 4);
    k_transpose_cast<<<dim3(1024 / 32, 512 / 32), 256, 0, stream>>>(Wq, Wqt, 512, 1024);
    k_transpose_cast<<<dim3(1024 / 32, 512 / 32), 256, 0, stream>>>(Wk, Wkt, 512, 1024);
    k_wvo<<<128, 256, 0, stream>>>(Wv, Wo, Wvot);
    k_gemm<<<dim3(128, 8), 256, 0, stream>>>(S2h, Wqt, Qh, 16384, 1024, 512);
    k_gemm<<<dim3(128, 8), 256, 0, stream>>>(S1h, Wkt, Kh, 16384, 1024, 512);
    k_gemm_vt<<<dim3(128, 4), 256, 0, stream>>>(S1h, Wvot, bo, Vt, 16384, 512, 512);
    k_attn<<<256, 512, 0, stream>>>(Qh, Kh, Vt, Out);
}

// Round 2
// 489.927 us; speedup vs baseline: 1.2123x; 1.2123x over previous
//
#include <hip/hip_runtime.h>

// CrossAttention: out = softmax((S2 Wq)(S1 Wk)^T) (S1 Wv) Wo + bo
// Refactored: Wvo = Wv@Wo (512x512);  V'' = S1@Wvo + bo;  out = softmax(QK^T) @ V''
// fp16 MFMA (16x16x32), fp32 accumulate. Attention: 128-key tiles, 4 sacc
// chains/wave, register softmax with shfl reductions, 10 barriers/kt.

typedef _Float16 h_t;
typedef _Float16 h8 __attribute__((ext_vector_type(8)));
typedef _Float16 h4 __attribute__((ext_vector_type(4)));
typedef float f4 __attribute__((ext_vector_type(4)));

#define MFMA16(a, b, c) __builtin_amdgcn_mfma_f32_16x16x32_f16(a, b, c, 0, 0, 0)

typedef const __attribute__((address_space(1))) void* gas_t;
typedef __attribute__((address_space(3))) void* las_t;

__device__ __forceinline__ void gl2lds16(const void* g, void* l) {
    __builtin_amdgcn_global_load_lds((gas_t)g, (las_t)l, 16, 0, 0);
}

// ---------------- merged cast fp32 -> fp16: S1, S2, Wv ----------------
__global__ __launch_bounds__(256) void k_cast3(const float* __restrict__ S1,
                                               const float* __restrict__ S2,
                                               const float* __restrict__ Wv,
                                               h_t* __restrict__ S1h,
                                               h_t* __restrict__ S2h,
                                               h_t* __restrict__ Wvh) {
    long i = (long)blockIdx.x * 256 + threadIdx.x;  // f4 index
    const long n = 2097152;                          // S1/S2 f4 count
    const float* src;
    h_t* dst;
    long off;
    if (i < n) { src = S1; dst = S1h; off = i; }
    else if (i < 2 * n) { src = S2; dst = S2h; off = i - n; }
    else { src = Wv; dst = Wvh; off = i - 2 * n; }
    float4 v = *((const float4*)src + off);
    h4 h = {(h_t)v.x, (h_t)v.y, (h_t)v.z, (h_t)v.w};
    *((h4*)dst + off) = h;
}

// ---------------- merged transpose+cast: Wq, Wk, Wo -> [N][K] f16 ----------------
__global__ __launch_bounds__(256) void k_transpose3(const float* __restrict__ Wq,
                                                    const float* __restrict__ Wk,
                                                    const float* __restrict__ Wo,
                                                    h_t* __restrict__ Wqt,
                                                    h_t* __restrict__ Wkt,
                                                    h_t* __restrict__ Wot) {
    const float* in;
    h_t* out;
    int K, N;
    if (blockIdx.z == 0) { in = Wq; out = Wqt; K = 512; N = 1024; }
    else if (blockIdx.z == 1) { in = Wk; out = Wkt; K = 512; N = 1024; }
    else { in = Wo; out = Wot; K = 1024; N = 512; }
    int kb = blockIdx.y * 32, nb = blockIdx.x * 32;
    if (kb >= K || nb >= N) return;
    __shared__ float tile[32][33];
    int x = threadIdx.x & 31, y = threadIdx.x >> 5;
#pragma unroll
    for (int j = 0; j < 4; j++)
        tile[y + j * 8][x] = in[(size_t)(kb + y + j * 8) * N + nb + x];
    __syncthreads();
#pragma unroll
    for (int j = 0; j < 4; j++)
        out[(size_t)(nb + y + j * 8) * K + kb + x] = (h_t)tile[x][y + j * 8];
}

// ---------------- m97-style NT GEMM: C[M][N] f16 = A[M][K] x Bt[N][K]^T ------------
__global__ __launch_bounds__(256) void k_gemm(const h_t* __restrict__ A,
                                              const h_t* __restrict__ Bt,
                                              h_t* __restrict__ C,
                                              int M, int N, int K) {
    __shared__ h_t As[128 * 64];
    __shared__ h_t Bs[128 * 64];
    int t = threadIdx.x, w = t >> 6, lane = t & 63;
    int q16 = lane >> 4, l16 = lane & 15;
    size_t m0 = (size_t)blockIdx.x * 128, n0 = (size_t)blockIdx.y * 128;
    int wr = (w >> 1) * 64, wc = (w & 1) * 64;
    f4 acc[4][4] = {};

    for (int k0 = 0; k0 < K; k0 += 64) {
#pragma unroll
        for (int j = 0; j < 4; j++) {
            int q = w * 4 + j;
            int row = q * 8 + (lane >> 3);
            int ks = (((lane & 7) ^ (row & 7)) << 3);
            gl2lds16(A + (m0 + row) * K + k0 + ks, &As[q * 512]);
            gl2lds16(Bt + (n0 + row) * K + k0 + ks, &Bs[q * 512]);
        }
        __syncthreads();
#pragma unroll
        for (int ks = 0; ks < 2; ks++) {
            h8 av[4], bv[4];
#pragma unroll
            for (int i = 0; i < 4; i++) {
                int row = wr + i * 16 + l16;
                int ch = ks * 4 + q16;
                av[i] = *(const h8*)&As[row * 64 + ((ch ^ (row & 7)) << 3)];
            }
#pragma unroll
            for (int j = 0; j < 4; j++) {
                int row = wc + j * 16 + l16;
                int ch = ks * 4 + q16;
                bv[j] = *(const h8*)&Bs[row * 64 + ((ch ^ (row & 7)) << 3)];
            }
#pragma unroll
            for (int i = 0; i < 4; i++)
#pragma unroll
                for (int j = 0; j < 4; j++)
                    acc[i][j] = MFMA16(av[i], bv[j], acc[i][j]);
        }
        __syncthreads();
    }
#pragma unroll
    for (int i = 0; i < 4; i++) {
        size_t r0 = m0 + wr + i * 16 + q16 * 4;
#pragma unroll
        for (int j = 0; j < 4; j++) {
            size_t c = n0 + wc + j * 16 + l16;
#pragma unroll
            for (int r = 0; r < 4; r++)
                C[(r0 + r) * N + c] = (h_t)acc[i][j][r];
        }
    }
}

// ---------------- V'' GEMM: +bias, transposed store Vt[b][d][n] -------------------
__global__ __launch_bounds__(256) void k_gemm_vt(const h_t* __restrict__ A,
                                                 const h_t* __restrict__ Bt,
                                                 const float* __restrict__ bo,
                                                 h_t* __restrict__ Vt,
                                                 int M, int N, int K) {
    __shared__ h_t As[128 * 64];
    __shared__ h_t Bs[128 * 64];
    int t = threadIdx.x, w = t >> 6, lane = t & 63;
    int q16 = lane >> 4, l16 = lane & 15;
    size_t m0 = (size_t)blockIdx.x * 128, n0 = (size_t)blockIdx.y * 128;
    int wr = (w >> 1) * 64, wc = (w & 1) * 64;
    f4 acc[4][4] = {};

    for (int k0 = 0; k0 < K; k0 += 64) {
#pragma unroll
        for (int j = 0; j < 4; j++) {
            int q = w * 4 + j;
            int row = q * 8 + (lane >> 3);
            int ks = (((lane & 7) ^ (row & 7)) << 3);
            gl2lds16(A + (m0 + row) * K + k0 + ks, &As[q * 512]);
            gl2lds16(Bt + (n0 + row) * K + k0 + ks, &Bs[q * 512]);
        }
        __syncthreads();
#pragma unroll
        for (int ks = 0; ks < 2; ks++) {
            h8 av[4], bv[4];
#pragma unroll
            for (int i = 0; i < 4; i++) {
                int row = wr + i * 16 + l16;
                int ch = ks * 4 + q16;
                av[i] = *(const h8*)&As[row * 64 + ((ch ^ (row & 7)) << 3)];
            }
#pragma unroll
            for (int j = 0; j < 4; j++) {
                int row = wc + j * 16 + l16;
                int ch = ks * 4 + q16;
                bv[j] = *(const h8*)&Bs[row * 64 + ((ch ^ (row & 7)) << 3)];
            }
#pragma unroll
            for (int i = 0; i < 4; i++)
#pragma unroll
                for (int j = 0; j < 4; j++)
                    acc[i][j] = MFMA16(av[i], bv[j], acc[i][j]);
        }
        __syncthreads();
    }
#pragma unroll
    for (int i = 0; i < 4; i++) {
        size_t gm = m0 + wr + i * 16 + q16 * 4;
        size_t b = gm >> 11;
        size_t n = gm & 2047;
#pragma unroll
        for (int j = 0; j < 4; j++) {
            size_t d = n0 + wc + j * 16 + l16;
            float bias = bo[d];
            h4 hv = {(h_t)(acc[i][j][0] + bias), (h_t)(acc[i][j][1] + bias),
                     (h_t)(acc[i][j][2] + bias), (h_t)(acc[i][j][3] + bias)};
            *(h4*)&Vt[(b * 512 + d) * 2048 + n] = hv;
        }
    }
}

// ---------------- fused flash attention ----------------
// 256 blocks (1/CU), 512 threads (8 waves = 4 row-bands x 2 col-halves).
// 128-key tiles: QK has 4 independent sacc chains/wave; softmax in registers
// (shfl row-reduce + one LDS Stat round for cross-wave combine); P -> LDS for
// the C-layout -> A-layout transpose; PV 16 chains/wave, V from L2/L3.
__global__ __launch_bounds__(512) void k_attn(const h_t* __restrict__ Qh,
                                              const h_t* __restrict__ Kh,
                                              const h_t* __restrict__ Vt,
                                              float* __restrict__ Out) {
    __shared__ h_t Ks[128 * 256];     // 64 KB, XOR-swizzled 16B chunks
    __shared__ h_t Ps[64 * 136];      // 17 KB probs, padded stride
    __shared__ float Stat[2][64][2];  // per-col-half (max, sumexp)
    __shared__ float arow[64];        // broadcast alpha / final l

    int t = threadIdx.x, w = t >> 6, lane = t & 63;
    int q16 = lane >> 4, l16 = lane & 15;
    int rb = w & 3, ch = w >> 2;
    int b = blockIdx.x & 7;
    int qt = blockIdx.x >> 3;
    int q0 = qt * 64;

    // Q fragments: rows rb*16+l16, k = f*32 + q16*8 .. +8 (128 VGPR)
    h8 qf[32];
    {
        size_t qrow = (size_t)b * 2048 + q0 + rb * 16 + l16;
        const h_t* qp = Qh + qrow * 1024 + q16 * 8;
#pragma unroll
        for (int f = 0; f < 32; f++) qf[f] = *(const h8*)(qp + f * 32);
    }
    f4 oacc[4][4] = {};
    float mrun[4] = {-1e30f, -1e30f, -1e30f, -1e30f};
    float lrun[4] = {0.f, 0.f, 0.f, 0.f};
    const h_t* Kbase = Kh + (size_t)b * 2048 * 1024;
    const h_t* Vbase = Vt + (size_t)b * 512 * 2048;

    for (int kt = 0; kt < 16; kt++) {
        int kb = kt * 128;
        f4 sacc[4] = {};
        // ---- S = Q K^T over inner 1024, staged in 4 chunks of 256 ----
#pragma unroll
        for (int c4 = 0; c4 < 4; c4++) {
#pragma unroll
            for (int j = 0; j < 8; j++) {
                int qch = w * 8 + j;
                int row = qch * 2 + (lane >> 5);
                int kg = lane & 31;
                gl2lds16(Kbase + (size_t)(kb + row) * 1024 + c4 * 256 +
                             ((kg ^ (row & 7)) << 3),
                         &Ks[qch * 512]);
            }
            __syncthreads();
#pragma unroll
            for (int ks = 0; ks < 8; ks++) {
#pragma unroll
                for (int j = 0; j < 4; j++) {
                    int row = (ch * 4 + j) * 16 + l16;
                    int c = ks * 4 + q16;
                    h8 bv = *(const h8*)&Ks[row * 256 + ((c ^ (row & 7)) << 3)];
                    sacc[j] = MFMA16(qf[c4 * 8 + ks], bv, sacc[j]);
                }
            }
            __syncthreads();
        }
        // ---- softmax in registers ----
        float mt[4], st[4];
#pragma unroll
        for (int r = 0; r < 4; r++)
            mt[r] = fmaxf(fmaxf(sacc[0][r], sacc[1][r]),
                          fmaxf(sacc[2][r], sacc[3][r]));
#pragma unroll
        for (int m = 1; m <= 8; m <<= 1)
#pragma unroll
            for (int r = 0; r < 4; r++)
                mt[r] = fmaxf(mt[r], __shfl_xor(mt[r], m, 64));
#pragma unroll
        for (int r = 0; r < 4; r++) {
            float s = 0.f;
#pragma unroll
            for (int j = 0; j < 4; j++) {
                float e = __expf(sacc[j][r] - mt[r]);
                sacc[j][r] = e;
                s += e;
            }
            st[r] = s;
        }
#pragma unroll
        for (int m = 1; m <= 8; m <<= 1)
#pragma unroll
            for (int r = 0; r < 4; r++) st[r] += __shfl_xor(st[r], m, 64);
        if (l16 == 0) {
#pragma unroll
            for (int r = 0; r < 4; r++) {
                int row = rb * 16 + q16 * 4 + r;
                Stat[ch][row][0] = mt[r];
                Stat[ch][row][1] = st[r];
            }
        }
        __syncthreads();
        float beta[4];
#pragma unroll
        for (int r = 0; r < 4; r++) {
            int row = rb * 16 + q16 * 4 + r;
            float m0 = Stat[0][row][0], s0 = Stat[0][row][1];
            float m1 = Stat[1][row][0], s1 = Stat[1][row][1];
            float mo = mrun[r];
            float mn = fmaxf(mo, fmaxf(m0, m1));
            float a = __expf(mo - mn);
            lrun[r] = lrun[r] * a + s0 * __expf(m0 - mn) + s1 * __expf(m1 - mn);
            mrun[r] = mn;
            beta[r] = __expf(mt[r] - mn);
            if (ch == 0 && l16 == 0) arow[row] = a;
        }
        // P (scaled to new running max) -> LDS, C-layout -> A-layout transpose
#pragma unroll
        for (int j = 0; j < 4; j++)
#pragma unroll
            for (int r = 0; r < 4; r++)
                Ps[(rb * 16 + q16 * 4 + r) * 136 + (ch * 4 + j) * 16 + l16] =
                    (h_t)(sacc[j][r] * beta[r]);
        __syncthreads();
        // ---- rescale O, then O += P @ V'' (wave owns 64 of 512 d-cols) ----
#pragma unroll
        for (int i = 0; i < 4; i++) {
#pragma unroll
            for (int r = 0; r < 4; r++) {
                float a = arow[i * 16 + q16 * 4 + r];
#pragma unroll
                for (int j = 0; j < 4; j++) oacc[i][j][r] *= a;
            }
        }
#pragma unroll
        for (int kstep = 0; kstep < 4; kstep++) {
            h8 pf[4], vf[4];
#pragma unroll
            for (int j = 0; j < 4; j++) {
                int d = w * 64 + j * 16 + l16;
                vf[j] = *(const h8*)(Vbase + (size_t)d * 2048 + kb + kstep * 32 +
                                     q16 * 8);
            }
#pragma unroll
            for (int i = 0; i < 4; i++)
                pf[i] = *(const h8*)&Ps[(i * 16 + l16) * 136 + kstep * 32 + q16 * 8];
#pragma unroll
            for (int i = 0; i < 4; i++)
#pragma unroll
                for (int j = 0; j < 4; j++)
                    oacc[i][j] = MFMA16(pf[i], vf[j], oacc[i][j]);
        }
        // no trailing barrier: next kt's Ks staging is fenced by its own barrier,
        // and Ps/arow rewrites happen only after next kt's Stat barrier.
    }
    // ---- epilogue: broadcast l, normalize, store fp32 ----
    __syncthreads();
    if (ch == 0 && l16 == 0) {
#pragma unroll
        for (int r = 0; r < 4; r++) arow[rb * 16 + q16 * 4 + r] = lrun[r];
    }
    __syncthreads();
#pragma unroll
    for (int i = 0; i < 4; i++) {
#pragma unroll
        for (int r = 0; r < 4; r++) {
            int row = i * 16 + q16 * 4 + r;
            float inv = 1.f / arow[row];
            size_t orow = ((size_t)b * 2048 + q0 + row) * 512;
#pragma unroll
            for (int j = 0; j < 4; j++) {
                int d = w * 64 + j * 16 + l16;
                Out[orow + d] = oacc[i][j][r] * inv;
            }
        }
    }
}

// ---------------- host ----------------
extern "C" void kernel_launch(void* const* d_in, const int* in_sizes, int n_in,
                              void* d_out, int out_size, void* d_ws, size_t ws_size,
                              hipStream_t stream) {
    const float* S1 = (const float*)d_in[0];
    const float* S2 = (const float*)d_in[1];
    const float* Wq = (const float*)d_in[2];
    const float* Wk = (const float*)d_in[3];
    const float* Wv = (const float*)d_in[4];
    const float* Wo = (const float*)d_in[5];
    const float* bo = (const float*)d_in[6];
    float* Out = (float*)d_out;

    char* ws = (char*)d_ws;
    h_t* S2h  = (h_t*)(ws);                 // 16 MB
    h_t* S1h  = (h_t*)(ws + 16777216);      // 16 MB
    h_t* Wqt  = (h_t*)(ws + 33554432);      // 1 MB
    h_t* Wkt  = (h_t*)(ws + 34603008);      // 1 MB
    h_t* Wvot = (h_t*)(ws + 35651584);      // 0.5 MB
    h_t* Qh   = (h_t*)(ws + 36175872);      // 32 MB
    h_t* Kh   = (h_t*)(ws + 69730304);      // 32 MB
    h_t* Vt   = (h_t*)(ws + 103284736);     // 16 MB -> end 120,061,952
    // Wot/Wvh alias the Qh region: they are dead before Qh is written.
    h_t* Wot  = (h_t*)(ws + 36175872);      // 1 MB  [512][1024]
    h_t* Wvh  = (h_t*)(ws + 37224448);      // 1 MB  [512][1024]

    k_cast3<<<16896, 256, 0, stream>>>(S1, S2, Wv, S1h, S2h, Wvh);
    k_transpose3<<<dim3(32, 32, 3), 256, 0, stream>>>(Wq, Wk, Wo, Wqt, Wkt, Wot);
    // Wvot[d][c] = sum_e Wot[d][e] * Wvh[c][e] = (Wv @ Wo)^T
    k_gemm<<<dim3(4, 4), 256, 0, stream>>>(Wot, Wvh, Wvot, 512, 512, 1024);
    k_gemm<<<dim3(128, 8), 256, 0, stream>>>(S2h, Wqt, Qh, 16384, 1024, 512);
    k_gemm<<<dim3(128, 8), 256, 0, stream>>>(S1h, Wkt, Kh, 16384, 1024, 512);
    k_gemm_vt<<<dim3(128, 4), 256, 0, stream>>>(S1h, Wvot, bo, Vt, 16384, 512, 512);
    k_attn<<<256, 512, 0, stream>>>(Qh, Kh, Vt, Out);
}